// Round 1
// baseline (221.184 us; speedup 1.0000x reference)
//
#include <hip/hip_runtime.h>
#include <cstdint>

// Problem constants (fixed by the reference: B=64, C*H*W = 524288, f32 in/out)
#define BROWS 64
#define NCOL  524288
#define CHUNKS 32
#define CHUNK  (NCOL / CHUNKS)   // 16384 elements per block
#define NV4    (CHUNK / 4)       // 4096 float4 per block
#define HBINS  4096              // 12-bit histogram
#define LCAP   2048              // per-block candidate staging (expect ~390)
#define ECAP   1024              // boundary-tie list (expect < 32)
#define MAXCAP 24576             // per-row candidate cap (expect ~12.4k)

// Workspace layout
#define CNT_OFF  ((size_t)(1u << 20))            // 64 u32 row counters
#define INFO_OFF ((size_t)((1u << 20) + 1024u))  // 64 x 4 u32 row info
#define CAND_OFF ((size_t)((1u << 20) + 8192u))  // u64 candidates [64][cap]

// Monotonic map: s1 > s2  <=>  fkey(s1) > fkey(s2)  (as uint32)
__device__ __forceinline__ uint32_t fkey(float s) {
  uint32_t b = __float_as_uint(s);
  return (b & 0x80000000u) ? ~b : (b | 0x80000000u);
}

__global__ __launch_bounds__(256) void k_zero(uint32_t* __restrict__ p, int n) {
  int i = blockIdx.x * 256 + threadIdx.x;
  if (i < n) p[i] = 0;
}

// P1: per-row 4096-bin histogram of key>>20, LDS-privatized per block.
__global__ __launch_bounds__(256) void k_hist(const float* __restrict__ x,
                                              const float* __restrict__ g,
                                              uint32_t* __restrict__ hist) {
  __shared__ uint32_t h[HBINS];
  for (int i = threadIdx.x; i < HBINS; i += 256) h[i] = 0;
  __syncthreads();
  int row = blockIdx.y, chunk = blockIdx.x;
  size_t base = (size_t)row * NCOL + (size_t)chunk * CHUNK;
  const float4* x4 = (const float4*)(x + base);
  const float4* g4 = (const float4*)(g + base);
  for (int i = threadIdx.x; i < NV4; i += 256) {
    float4 a = x4[i];
    float4 b = g4[i];
    atomicAdd(&h[fkey(a.x / 10.0f + b.x) >> 20], 1u);
    atomicAdd(&h[fkey(a.y / 10.0f + b.y) >> 20], 1u);
    atomicAdd(&h[fkey(a.z / 10.0f + b.z) >> 20], 1u);
    atomicAdd(&h[fkey(a.w / 10.0f + b.w) >> 20], 1u);
  }
  __syncthreads();
  uint32_t* gh = hist + (size_t)row * HBINS;
  for (int i = threadIdx.x; i < HBINS; i += 256) {
    uint32_t v = h[i];
    if (v) atomicAdd(&gh[i], v);
  }
}

// P2: per-row scan (from the top) -> coarse bin, count strictly above, needed-in-bin.
__global__ __launch_bounds__(256) void k_findbin(const uint32_t* __restrict__ hist,
                                                 const int* __restrict__ kptr,
                                                 uint32_t* __restrict__ rinfo) {
  __shared__ uint32_t h[HBINS];
  __shared__ uint32_t part[256];
  int row = blockIdx.x;
  const uint32_t* gh = hist + (size_t)row * HBINS;
  for (int i = threadIdx.x; i < HBINS; i += 256) h[i] = gh[i];
  __syncthreads();
  uint32_t s = 0;
  for (int j = 0; j < 16; ++j) s += h[threadIdx.x * 16 + j];
  part[threadIdx.x] = s;
  __syncthreads();
  if (threadIdx.x == 0) {
    uint32_t k = (uint32_t)(*kptr);
    uint32_t cum = 0;
    int seg = 255;
    for (; seg > 0; --seg) {
      if (cum + part[seg] >= k) break;
      cum += part[seg];
    }
    int bin = seg * 16 + 15;
    for (; bin > seg * 16; --bin) {
      if (cum + h[bin] >= k) break;
      cum += h[bin];
    }
    rinfo[row * 4 + 0] = (uint32_t)bin;  // coarse bin of k-th value
    rinfo[row * 4 + 1] = cum;            // count strictly above bin
    rinfo[row * 4 + 2] = k - cum;        // needed within bin (>= 1)
  }
}

// P3: stream again. Above bin -> relu(x); below -> 0; in-bin -> collect candidate.
__global__ __launch_bounds__(256) void k_select(const float* __restrict__ x,
                                                const float* __restrict__ g,
                                                const uint32_t* __restrict__ rinfo,
                                                uint64_t* __restrict__ cand,
                                                uint32_t* __restrict__ ccnt,
                                                float* __restrict__ out, int cap) {
  __shared__ uint64_t lbuf[LCAP];
  __shared__ uint32_t lcnt, lbase;
  int row = blockIdx.y, chunk = blockIdx.x;
  uint32_t selbin = rinfo[row * 4 + 0];
  if (threadIdx.x == 0) lcnt = 0;
  __syncthreads();
  size_t base = (size_t)row * NCOL + (size_t)chunk * CHUNK;
  const float4* x4 = (const float4*)(x + base);
  const float4* g4 = (const float4*)(g + base);
  float4* o4 = (float4*)(out + base);
  for (int i = threadIdx.x; i < NV4; i += 256) {
    float4 a = x4[i];
    float4 b = g4[i];
    uint32_t f0 = fkey(a.x / 10.0f + b.x);
    uint32_t f1 = fkey(a.y / 10.0f + b.y);
    uint32_t f2 = fkey(a.z / 10.0f + b.z);
    uint32_t f3 = fkey(a.w / 10.0f + b.w);
    uint32_t b0 = f0 >> 20, b1 = f1 >> 20, b2 = f2 >> 20, b3 = f3 >> 20;
    float4 o;
    o.x = (b0 > selbin) ? fmaxf(a.x, 0.0f) : 0.0f;
    o.y = (b1 > selbin) ? fmaxf(a.y, 0.0f) : 0.0f;
    o.z = (b2 > selbin) ? fmaxf(a.z, 0.0f) : 0.0f;
    o.w = (b3 > selbin) ? fmaxf(a.w, 0.0f) : 0.0f;
    o4[i] = o;
    uint32_t li = (uint32_t)(chunk * CHUNK + i * 4);
    if (b0 == selbin) { uint32_t p = atomicAdd(&lcnt, 1u); if (p < LCAP) lbuf[p] = ((uint64_t)f0 << 32) | (li + 0u); }
    if (b1 == selbin) { uint32_t p = atomicAdd(&lcnt, 1u); if (p < LCAP) lbuf[p] = ((uint64_t)f1 << 32) | (li + 1u); }
    if (b2 == selbin) { uint32_t p = atomicAdd(&lcnt, 1u); if (p < LCAP) lbuf[p] = ((uint64_t)f2 << 32) | (li + 2u); }
    if (b3 == selbin) { uint32_t p = atomicAdd(&lcnt, 1u); if (p < LCAP) lbuf[p] = ((uint64_t)f3 << 32) | (li + 3u); }
  }
  __syncthreads();
  uint32_t cnt = lcnt < LCAP ? lcnt : LCAP;
  if (threadIdx.x == 0) lbase = atomicAdd(&ccnt[row], cnt);
  __syncthreads();
  uint64_t* dst = cand + (size_t)row * (size_t)cap;
  uint32_t bse = lbase;
  for (uint32_t i = threadIdx.x; i < cnt; i += 256) {
    uint32_t p = bse + i;
    if (p < (uint32_t)cap) dst[p] = lbuf[i];
  }
}

// P4: per-row refine: sub-histogram on key bits 8..19, then sort the boundary
// sub-bin by (key desc, idx asc) -- exact jax.lax.top_k tie semantics.
__global__ __launch_bounds__(256) void k_finalize(const float* __restrict__ x,
                                                  const uint64_t* __restrict__ cand,
                                                  const uint32_t* __restrict__ ccnt,
                                                  const uint32_t* __restrict__ rinfo,
                                                  float* __restrict__ out, int cap) {
  __shared__ uint32_t h2[HBINS];
  __shared__ uint32_t part[256];
  __shared__ uint64_t elist[ECAP];
  __shared__ uint32_t ecnt;
  __shared__ int s_sub, s_need2;
  int row = blockIdx.x;
  uint32_t cnt = ccnt[row];
  if (cnt > (uint32_t)cap) cnt = (uint32_t)cap;
  uint32_t need = rinfo[row * 4 + 2];
  for (int i = threadIdx.x; i < HBINS; i += 256) h2[i] = 0;
  if (threadIdx.x == 0) ecnt = 0;
  __syncthreads();
  const uint64_t* c = cand + (size_t)row * (size_t)cap;
  for (uint32_t i = threadIdx.x; i < cnt; i += 256)
    atomicAdd(&h2[((uint32_t)(c[i] >> 32) >> 8) & 0xFFFu], 1u);
  __syncthreads();
  uint32_t s = 0;
  for (int j = 0; j < 16; ++j) s += h2[threadIdx.x * 16 + j];
  part[threadIdx.x] = s;
  __syncthreads();
  if (threadIdx.x == 0) {
    uint32_t cum = 0;
    int seg = 255;
    for (; seg > 0; --seg) {
      if (cum + part[seg] >= need) break;
      cum += part[seg];
    }
    int bin = seg * 16 + 15;
    for (; bin > seg * 16; --bin) {
      if (cum + h2[bin] >= need) break;
      cum += h2[bin];
    }
    s_sub = bin;
    s_need2 = (int)(need - cum);
  }
  __syncthreads();
  int sub = s_sub, need2 = s_need2;
  size_t rb = (size_t)row * NCOL;
  for (uint32_t i = threadIdx.x; i < cnt; i += 256) {
    uint64_t e = c[i];
    int mid = (int)(((uint32_t)(e >> 32) >> 8) & 0xFFFu);
    uint32_t idx = (uint32_t)e;
    if (mid > sub) {
      out[rb + idx] = fmaxf(x[rb + idx], 0.0f);
    } else if (mid == sub) {
      uint32_t p = atomicAdd(&ecnt, 1u);
      if (p < ECAP) elist[p] = e ^ 0xFFFFFFFFull;  // key desc, idx asc under u64 desc
    }
  }
  __syncthreads();
  int m = (int)(ecnt < (uint32_t)ECAP ? ecnt : (uint32_t)ECAP);
  // odd-even transposition sort, descending; m passes guarantee sorted
  for (int pass = 0; pass < m; ++pass) {
    for (int i = threadIdx.x; 2 * i + (pass & 1) + 1 < m; i += 256) {
      int a = 2 * i + (pass & 1);
      uint64_t va = elist[a], vb = elist[a + 1];
      if (vb > va) { elist[a] = vb; elist[a + 1] = va; }
    }
    __syncthreads();
  }
  int w = need2 < m ? need2 : m;
  for (int i = threadIdx.x; i < w; i += 256) {
    uint32_t idx = ~(uint32_t)elist[i];
    out[rb + idx] = fmaxf(x[rb + idx], 0.0f);
  }
}

extern "C" void kernel_launch(void* const* d_in, const int* in_sizes, int n_in,
                              void* d_out, int out_size, void* d_ws, size_t ws_size,
                              hipStream_t stream) {
  const float* x = (const float*)d_in[0];
  const float* g = (const float*)d_in[1];
  const int* kptr = (const int*)d_in[2];
  float* out = (float*)d_out;
  char* ws = (char*)d_ws;

  uint32_t* hist = (uint32_t*)(ws);
  uint32_t* ccnt = (uint32_t*)(ws + CNT_OFF);
  uint32_t* rinfo = (uint32_t*)(ws + INFO_OFF);
  uint64_t* cand = (uint64_t*)(ws + CAND_OFF);

  long cap_avail = ((long)ws_size - (long)CAND_OFF) / (8 * BROWS);
  int cap = cap_avail < MAXCAP ? (int)cap_avail : MAXCAP;
  if (cap < 1) cap = 1;  // degenerate ws; should not happen

  // zero hist (1 MB) + row counters (contiguous region)
  int zwords = BROWS * HBINS + 64;
  k_zero<<<(zwords + 255) / 256, 256, 0, stream>>>((uint32_t*)ws, zwords);

  dim3 grid(CHUNKS, BROWS);
  k_hist<<<grid, 256, 0, stream>>>(x, g, hist);
  k_findbin<<<BROWS, 256, 0, stream>>>(hist, kptr, rinfo);
  k_select<<<grid, 256, 0, stream>>>(x, g, rinfo, cand, ccnt, out, cap);
  k_finalize<<<BROWS, 256, 0, stream>>>(x, cand, ccnt, rinfo, out, cap);
}